// Round 2
// baseline (1391.145 us; speedup 1.0000x reference)
//
#include <hip/hip_runtime.h>

__device__ __forceinline__ float silu(float x) { return x / (1.0f + __expf(-x)); }

constexpr int N_   = 16000;
constexpr int E_   = 256000;
constexpr int Fd   = 64;
constexpr int DEd  = 32;
constexpr int Wd   = 128;
constexpr int NIN  = 161;   // 2F + DE + 1
constexpr int NINP = 164;   // padded for float4
constexpr int NOUT = 192;   // 3F
constexpr int BE   = 8;     // edges per block

constexpr float SQ3f    = 1.7320508075688772f;
constexpr float INV_SQ3 = 0.5773502691896258f;
constexpr float INV_SQ2 = 0.7071067811865476f;
constexpr float INV_AVG = 0.0625f;  // 1/16

// output layout (flat, return order): out_s | out_v | p_s | p_v
constexpr int OFF_OS = 0;
constexpr int OFF_OV = N_;                 // 16000
constexpr int OFF_PS = OFF_OV + 3 * N_;    // 64000
constexpr int OFF_PV = OFF_PS + N_ * Fd;   // 1088000

// ---------------------------------------------------------------------------
// Kernel 1: node up-projection  h_s = node_s@W_up_s + b,  h_v = node_v ⊗ W_up_v
// one block (64 threads) per node
// ---------------------------------------------------------------------------
__global__ __launch_bounds__(64) void up_kernel(
    const float* __restrict__ node_s, const float* __restrict__ node_v,
    const float* __restrict__ W_up_s, const float* __restrict__ b_up_s,
    const float* __restrict__ W_up_v,
    float* __restrict__ h_s, float* __restrict__ h_v)
{
    __shared__ float ns[Fd];
    __shared__ float nv[Fd][3];
    const int n = blockIdx.x;
    const int g = threadIdx.x;

    ns[g] = node_s[n * Fd + g];
    for (int idx = g; idx < Fd * 3; idx += 64)
        nv[idx / 3][idx % 3] = node_v[n * Fd * 3 + idx];
    __syncthreads();

    float as = b_up_s[g];
    float a0 = 0.f, a1 = 0.f, a2 = 0.f;
    #pragma unroll 8
    for (int f = 0; f < Fd; f++) {
        float wss = W_up_s[f * Fd + g];
        as += ns[f] * wss;
        float wv = W_up_v[f * Fd + g];
        a0 += nv[f][0] * wv;
        a1 += nv[f][1] * wv;
        a2 += nv[f][2] * wv;
    }
    h_s[n * Fd + g] = as;
    h_v[n * Fd * 3 + g * 3 + 0] = a0;
    h_v[n * Fd * 3 + g * 3 + 1] = a1;
    h_v[n * Fd * 3 + g * 3 + 2] = a2;
}

// ---------------------------------------------------------------------------
// Kernel 2: per-edge MLP + tensor products + atomic scatter into agg arrays
// 8 edges per block, 128 threads
// ---------------------------------------------------------------------------
__global__ __launch_bounds__(128) void edge_kernel(
    const float* __restrict__ vectors, const float* __restrict__ lengths,
    const float* __restrict__ sef,
    const int* __restrict__ senders, const int* __restrict__ receivers,
    const float* __restrict__ W1, const float* __restrict__ b1,
    const float* __restrict__ W2, const float* __restrict__ b2,
    const float* __restrict__ W3, const float* __restrict__ b3,
    const float* __restrict__ h_s, const float* __restrict__ h_v,
    float* __restrict__ agg_s, float* __restrict__ agg_v)
{
    __shared__ float in_s[BE][NINP];
    __shared__ float mv_s[BE][Fd][3];
    __shared__ float h1_s[BE][Wd];
    __shared__ float h2_s[BE][Wd];
    __shared__ float mix_s[BE][NOUT];
    __shared__ float ev_s[BE][3];
    __shared__ int   recv_s[BE];
    __shared__ int   send_s[BE];

    const int tid = threadIdx.x;
    const int e0  = blockIdx.x * BE;

    if (tid < BE) {
        int ge = e0 + tid;
        recv_s[tid] = receivers[ge];
        send_s[tid] = senders[ge];
        ev_s[tid][0] = SQ3f * vectors[ge * 3 + 0];
        ev_s[tid][1] = SQ3f * vectors[ge * 3 + 1];
        ev_s[tid][2] = SQ3f * vectors[ge * 3 + 2];
    }
    __syncthreads();

    // stage mlp_in = [m_s(64), h_s[recv](64), sef(32), len(1)] and m_v
    for (int idx = tid; idx < BE * NIN; idx += 128) {
        int e = idx / NIN;
        int k = idx - e * NIN;
        int ge = e0 + e;
        float v;
        if (k < Fd)                 v = h_s[send_s[e] * Fd + k];
        else if (k < 2 * Fd)        v = h_s[recv_s[e] * Fd + (k - Fd)];
        else if (k < 2 * Fd + DEd)  v = sef[ge * DEd + (k - 2 * Fd)];
        else                        v = lengths[ge];
        in_s[e][k] = v;
    }
    for (int idx = tid; idx < BE * Fd * 3; idx += 128) {
        int e = idx / (Fd * 3);
        int j = idx - e * (Fd * 3);
        mv_s[e][j / 3][j % 3] = h_v[send_s[e] * (Fd * 3) + j];
    }
    __syncthreads();

    // GEMM1: 161 -> 128, silu
    {
        const int j = tid;
        float acc[BE];
        #pragma unroll
        for (int e = 0; e < BE; e++) acc[e] = 0.f;
        for (int k = 0; k < 160; k += 4) {
            float w0 = W1[(k + 0) * Wd + j];
            float w1 = W1[(k + 1) * Wd + j];
            float w2 = W1[(k + 2) * Wd + j];
            float w3 = W1[(k + 3) * Wd + j];
            #pragma unroll
            for (int e = 0; e < BE; e++) {
                const float4 v = *reinterpret_cast<const float4*>(&in_s[e][k]);
                acc[e] += v.x * w0 + v.y * w1 + v.z * w2 + v.w * w3;
            }
        }
        {
            float w = W1[160 * Wd + j];
            #pragma unroll
            for (int e = 0; e < BE; e++) acc[e] += in_s[e][160] * w;
        }
        float bb = b1[j];
        #pragma unroll
        for (int e = 0; e < BE; e++) h1_s[e][j] = silu(acc[e] + bb);
    }
    __syncthreads();

    // GEMM2: 128 -> 128, silu
    {
        const int j = tid;
        float acc[BE];
        #pragma unroll
        for (int e = 0; e < BE; e++) acc[e] = 0.f;
        for (int k = 0; k < Wd; k += 4) {
            float w0 = W2[(k + 0) * Wd + j];
            float w1 = W2[(k + 1) * Wd + j];
            float w2 = W2[(k + 2) * Wd + j];
            float w3 = W2[(k + 3) * Wd + j];
            #pragma unroll
            for (int e = 0; e < BE; e++) {
                const float4 v = *reinterpret_cast<const float4*>(&h1_s[e][k]);
                acc[e] += v.x * w0 + v.y * w1 + v.z * w2 + v.w * w3;
            }
        }
        float bb = b2[j];
        #pragma unroll
        for (int e = 0; e < BE; e++) h2_s[e][j] = silu(acc[e] + bb);
    }
    __syncthreads();

    // GEMM3: 128 -> 192 (linear)
    for (int c0 = tid; c0 < NOUT; c0 += 128) {
        float acc[BE];
        #pragma unroll
        for (int e = 0; e < BE; e++) acc[e] = 0.f;
        for (int k = 0; k < Wd; k += 4) {
            float w0 = W3[(k + 0) * NOUT + c0];
            float w1 = W3[(k + 1) * NOUT + c0];
            float w2 = W3[(k + 2) * NOUT + c0];
            float w3 = W3[(k + 3) * NOUT + c0];
            #pragma unroll
            for (int e = 0; e < BE; e++) {
                const float4 v = *reinterpret_cast<const float4*>(&h2_s[e][k]);
                acc[e] += v.x * w0 + v.y * w1 + v.z * w2 + v.w * w3;
            }
        }
        float bb = b3[c0];
        #pragma unroll
        for (int e = 0; e < BE; e++) mix_s[e][c0] = acc[e] + bb;
    }
    __syncthreads();

    // epilogue: tensor products * mix, atomic scatter (already /16)
    {
        const int f    = tid & 63;
        const int half = tid >> 6;
        for (int e = 0; e < BE; e++) {
            const int r = recv_s[e];
            const float ev0 = ev_s[e][0], ev1 = ev_s[e][1], ev2 = ev_s[e][2];
            const float mv0 = mv_s[e][f][0], mv1 = mv_s[e][f][1], mv2 = mv_s[e][f][2];
            if (half == 0) {
                // tp_s and tp_v1
                float tps = (mv0 * ev0 + mv1 * ev1 + mv2 * ev2) * INV_SQ3
                            * mix_s[e][f] * INV_AVG;
                atomicAdd(&agg_s[r * Fd + f], tps);
                float ms = in_s[e][f];
                float m1 = mix_s[e][Fd + f] * INV_AVG;
                atomicAdd(&agg_v[r * (2 * Fd * 3) + f * 3 + 0], ms * ev0 * m1);
                atomicAdd(&agg_v[r * (2 * Fd * 3) + f * 3 + 1], ms * ev1 * m1);
                atomicAdd(&agg_v[r * (2 * Fd * 3) + f * 3 + 2], ms * ev2 * m1);
            } else {
                // tp_v2 = cross(m_v, ev)/sqrt2
                float m2 = mix_s[e][2 * Fd + f] * INV_SQ2 * INV_AVG;
                float cx = mv1 * ev2 - mv2 * ev1;
                float cy = mv2 * ev0 - mv0 * ev2;
                float cz = mv0 * ev1 - mv1 * ev0;
                atomicAdd(&agg_v[r * (2 * Fd * 3) + (Fd + f) * 3 + 0], cx * m2);
                atomicAdd(&agg_v[r * (2 * Fd * 3) + (Fd + f) * 3 + 1], cy * m2);
                atomicAdd(&agg_v[r * (2 * Fd * 3) + (Fd + f) * 3 + 2], cz * m2);
            }
        }
    }
}

// ---------------------------------------------------------------------------
// Kernel 3: node-side tail (dn, species scaling, pb, readout). 64 thr / node.
// ---------------------------------------------------------------------------
__global__ __launch_bounds__(64) void node_kernel(
    const float* __restrict__ agg_s, const float* __restrict__ agg_v,
    const int* __restrict__ specie,
    const float* __restrict__ W_dn_s, const float* __restrict__ b_dn_s,
    const float* __restrict__ W_dn_v,
    const float* __restrict__ w_sc_s, const float* __restrict__ w_sc_v,
    const float* __restrict__ W_pb_s, const float* __restrict__ b_pb_s,
    const float* __restrict__ W_pb_v,
    const float* __restrict__ W_r1_s, const float* __restrict__ b_r1_s,
    const float* __restrict__ W_r1_v,
    const float* __restrict__ W_r2_s, const float* __restrict__ b_r2,
    const float* __restrict__ W_r2_v,
    float* __restrict__ out)
{
    __shared__ float as_l[Fd];
    __shared__ float av_l[2 * Fd][3];
    __shared__ float scs[Fd];
    __shared__ float scv[Fd][3];
    __shared__ float ps[Fd];
    __shared__ float pv[Fd][3];

    const int n = blockIdx.x;
    const int g = threadIdx.x;

    as_l[g] = agg_s[n * Fd + g];
    for (int idx = g; idx < 2 * Fd * 3; idx += 64)
        av_l[idx / 3][idx % 3] = agg_v[n * (2 * Fd * 3) + idx];
    __syncthreads();

    // f_s, f_v
    float f_s = b_dn_s[g];
    #pragma unroll 8
    for (int f = 0; f < Fd; f++) f_s += as_l[f] * W_dn_s[f * Fd + g];
    float fv0 = 0.f, fv1 = 0.f, fv2 = 0.f;
    #pragma unroll 8
    for (int f = 0; f < 2 * Fd; f++) {
        float w = W_dn_v[f * Fd + g];
        fv0 += av_l[f][0] * w;
        fv1 += av_l[f][1] * w;
        fv2 += av_l[f][2] * w;
    }

    // species scaling
    float vv = (fv0 * fv0 + fv1 * fv1 + fv2 * fv2) * INV_SQ3;
    int sp = specie[n];
    float ws0 = w_sc_s[sp * 3 * Fd + 0 * Fd + g];
    float ws1 = w_sc_s[sp * 3 * Fd + 1 * Fd + g];
    float ws2 = w_sc_s[sp * 3 * Fd + 2 * Fd + g];
    float wv0 = w_sc_v[sp * 2 * Fd + 0 * Fd + g];
    float wv1 = w_sc_v[sp * 2 * Fd + 1 * Fd + g];
    float sc_s = ws0 * f_s + ws1 * f_s * f_s + ws2 * vv;
    float kv = wv0 + wv1 * f_s;
    scs[g] = sc_s;
    scv[g][0] = kv * fv0;
    scv[g][1] = kv * fv1;
    scv[g][2] = kv * fv2;
    __syncthreads();

    // p_s, p_v
    float p_s = b_pb_s[g];
    float pv0 = 0.f, pv1 = 0.f, pv2 = 0.f;
    #pragma unroll 8
    for (int f = 0; f < Fd; f++) {
        float wps = W_pb_s[f * Fd + g];
        p_s += scs[f] * wps;
        float wpv = W_pb_v[f * Fd + g];
        pv0 += scv[f][0] * wpv;
        pv1 += scv[f][1] * wpv;
        pv2 += scv[f][2] * wpv;
    }
    ps[g] = p_s;
    pv[g][0] = pv0; pv[g][1] = pv1; pv[g][2] = pv2;

    // outputs p_s, p_v
    out[OFF_PS + n * Fd + g] = p_s;
    out[OFF_PV + n * Fd * 3 + g * 3 + 0] = pv0;
    out[OFF_PV + n * Fd * 3 + g * 3 + 1] = pv1;
    out[OFF_PV + n * Fd * 3 + g * 3 + 2] = pv2;
    __syncthreads();

    // readout: r_s (128), r_v (64x3)
    float r0 = b_r1_s[g];
    float r1 = b_r1_s[g + Fd];
    float rv0 = 0.f, rv1 = 0.f, rv2 = 0.f;
    #pragma unroll 8
    for (int f = 0; f < Fd; f++) {
        float p = ps[f];
        r0 += p * W_r1_s[f * 2 * Fd + g];
        r1 += p * W_r1_s[f * 2 * Fd + g + Fd];
        float wrv = W_r1_v[f * Fd + g];
        rv0 += pv[f][0] * wrv;
        rv1 += pv[f][1] * wrv;
        rv2 += pv[f][2] * wrv;
    }
    float act  = silu(r0);
    float gate = silu(r1);
    float o_s = act * W_r2_s[g];
    float wr2v = W_r2_v[g];
    float ov0 = gate * rv0 * wr2v;
    float ov1 = gate * rv1 * wr2v;
    float ov2 = gate * rv2 * wr2v;

    // wave-64 reduction
    #pragma unroll
    for (int off = 32; off > 0; off >>= 1) {
        o_s += __shfl_down(o_s, off);
        ov0 += __shfl_down(ov0, off);
        ov1 += __shfl_down(ov1, off);
        ov2 += __shfl_down(ov2, off);
    }
    if (g == 0) {
        out[OFF_OS + n] = o_s + b_r2[0];
        out[OFF_OV + n * 3 + 0] = ov0;
        out[OFF_OV + n * 3 + 1] = ov1;
        out[OFF_OV + n * 3 + 2] = ov2;
    }
}

// ---------------------------------------------------------------------------
extern "C" void kernel_launch(void* const* d_in, const int* in_sizes, int n_in,
                              void* d_out, int out_size, void* d_ws, size_t ws_size,
                              hipStream_t stream)
{
    const float* vectors  = (const float*)d_in[0];
    const float* lengths  = (const float*)d_in[1];
    const float* node_s   = (const float*)d_in[2];
    const float* node_v   = (const float*)d_in[3];
    const float* sef      = (const float*)d_in[4];
    const int*  specie    = (const int*)d_in[5];
    const int*  senders   = (const int*)d_in[6];
    const int*  receivers = (const int*)d_in[7];
    const float* W_up_s   = (const float*)d_in[8];
    const float* b_up_s   = (const float*)d_in[9];
    const float* W_up_v   = (const float*)d_in[10];
    const float* mlp_W1   = (const float*)d_in[11];
    const float* mlp_b1   = (const float*)d_in[12];
    const float* mlp_W2   = (const float*)d_in[13];
    const float* mlp_b2   = (const float*)d_in[14];
    const float* mlp_W3   = (const float*)d_in[15];
    const float* mlp_b3   = (const float*)d_in[16];
    const float* W_dn_s   = (const float*)d_in[17];
    const float* b_dn_s   = (const float*)d_in[18];
    const float* W_dn_v   = (const float*)d_in[19];
    const float* w_sc_s   = (const float*)d_in[20];
    const float* w_sc_v   = (const float*)d_in[21];
    const float* W_pb_s   = (const float*)d_in[22];
    const float* b_pb_s   = (const float*)d_in[23];
    const float* W_pb_v   = (const float*)d_in[24];
    const float* W_r1_s   = (const float*)d_in[25];
    const float* b_r1_s   = (const float*)d_in[26];
    const float* W_r1_v   = (const float*)d_in[27];
    const float* W_r2_s   = (const float*)d_in[28];
    const float* b_r2     = (const float*)d_in[29];
    const float* W_r2_v   = (const float*)d_in[30];

    // workspace layout (fp32): h_s | h_v | agg_s | agg_v  = N*704 floats ≈ 45 MB
    float* h_s   = (float*)d_ws;
    float* h_v   = h_s + (size_t)N_ * Fd;
    float* agg_s = h_v + (size_t)N_ * Fd * 3;
    float* agg_v = agg_s + (size_t)N_ * Fd;

    float* out = (float*)d_out;

    hipMemsetAsync(agg_s, 0, (size_t)N_ * (Fd + 2 * Fd * 3) * sizeof(float), stream);

    up_kernel<<<N_, 64, 0, stream>>>(node_s, node_v, W_up_s, b_up_s, W_up_v, h_s, h_v);

    edge_kernel<<<E_ / BE, 128, 0, stream>>>(
        vectors, lengths, sef, senders, receivers,
        mlp_W1, mlp_b1, mlp_W2, mlp_b2, mlp_W3, mlp_b3,
        h_s, h_v, agg_s, agg_v);

    node_kernel<<<N_, 64, 0, stream>>>(
        agg_s, agg_v, specie,
        W_dn_s, b_dn_s, W_dn_v, w_sc_s, w_sc_v,
        W_pb_s, b_pb_s, W_pb_v, W_r1_s, b_r1_s, W_r1_v,
        W_r2_s, b_r2, W_r2_v, out);
}

// Round 3
// 1266.837 us; speedup vs baseline: 1.0981x; 1.0981x over previous
//
#include <hip/hip_runtime.h>

typedef short bf16x8 __attribute__((ext_vector_type(8)));
typedef float f32x4  __attribute__((ext_vector_type(4)));
typedef unsigned short ushort_t;

__device__ __forceinline__ float silu(float x) { return x / (1.0f + __expf(-x)); }

// RNE float -> bf16 bits
__device__ __forceinline__ ushort_t f2bs(float x) {
    union { float f; unsigned int u; } v; v.f = x;
    unsigned int r = v.u + 0x7FFF + ((v.u >> 16) & 1);
    return (ushort_t)(r >> 16);
}
__device__ __forceinline__ float bs2f(ushort_t x) {
    union { unsigned int u; float f; } v; v.u = ((unsigned int)x) << 16; return v.f;
}

constexpr int N_   = 16000;
constexpr int E_   = 256000;
constexpr int Fd   = 64;
constexpr int Wd   = 128;

constexpr float SQ3f    = 1.7320508075688772f;
constexpr float INV_SQ3 = 0.5773502691896258f;
constexpr float INV_SQ2 = 0.7071067811865476f;
constexpr float INV_AVG = 0.0625f;  // 1/16

// output layout (flat, return order): out_s | out_v | p_s | p_v
constexpr int OFF_OS = 0;
constexpr int OFF_OV = N_;
constexpr int OFF_PS = OFF_OV + 3 * N_;
constexpr int OFF_PV = OFF_PS + N_ * Fd;

// packed-weight region sizes (ushorts)
constexpr int W1P_SZ = 6 * 8 * 512;   // 6 K-chunks x 8 N-tiles x 64 lanes x 8
constexpr int W2P_SZ = 4 * 8 * 512;
constexpr int W3P_SZ = 4 * 12 * 512;

// ---------------------------------------------------------------------------
// pack weights fp32 -> bf16 MFMA B-fragment order
// B-frag: lane l holds B[k = c*32 + (l>>4)*8 + j][n = t*16 + (l&15)], j=0..7
// ---------------------------------------------------------------------------
__global__ __launch_bounds__(256) void pack_kernel(
    const float* __restrict__ W1, const float* __restrict__ W2,
    const float* __restrict__ W3,
    ushort_t* __restrict__ W1p, ushort_t* __restrict__ W2p,
    ushort_t* __restrict__ W3p)
{
    int idx = blockIdx.x * 256 + threadIdx.x;  // 65536 total
    if (idx < W1P_SZ) {
        int j = idx & 7, lane = (idx >> 3) & 63, tile = idx >> 9;
        int c = tile >> 3, t = tile & 7;
        int k = c * 32 + (lane >> 4) * 8 + j;
        int n = t * 16 + (lane & 15);
        W1p[idx] = f2bs(k < 161 ? W1[k * 128 + n] : 0.f);
    } else if (idx < W1P_SZ + W2P_SZ) {
        int q = idx - W1P_SZ;
        int j = q & 7, lane = (q >> 3) & 63, tile = q >> 9;
        int c = tile >> 3, t = tile & 7;
        int k = c * 32 + (lane >> 4) * 8 + j;
        int n = t * 16 + (lane & 15);
        W2p[q] = f2bs(W2[k * 128 + n]);
    } else {
        int q = idx - W1P_SZ - W2P_SZ;
        int j = q & 7, lane = (q >> 3) & 63, tile = q >> 9;
        int c = tile / 12, t = tile % 12;
        int k = c * 32 + (lane >> 4) * 8 + j;
        int n = t * 16 + (lane & 15);
        W3p[q] = f2bs(W3[k * 192 + n]);
    }
}

// ---------------------------------------------------------------------------
// Kernel 1: node up-projection. h_s written as bf16 (GEMM A operand + m_s),
// h_v stays fp32. One block (64 threads) per node.
// ---------------------------------------------------------------------------
__global__ __launch_bounds__(64) void up_kernel(
    const float* __restrict__ node_s, const float* __restrict__ node_v,
    const float* __restrict__ W_up_s, const float* __restrict__ b_up_s,
    const float* __restrict__ W_up_v,
    ushort_t* __restrict__ hs_bf, float* __restrict__ h_v)
{
    __shared__ float ns[Fd];
    __shared__ float nv[Fd][3];
    const int n = blockIdx.x;
    const int g = threadIdx.x;

    ns[g] = node_s[n * Fd + g];
    for (int idx = g; idx < Fd * 3; idx += 64)
        nv[idx / 3][idx % 3] = node_v[n * Fd * 3 + idx];
    __syncthreads();

    float as = b_up_s[g];
    float a0 = 0.f, a1 = 0.f, a2 = 0.f;
    #pragma unroll 8
    for (int f = 0; f < Fd; f++) {
        float wss = W_up_s[f * Fd + g];
        as += ns[f] * wss;
        float wv = W_up_v[f * Fd + g];
        a0 += nv[f][0] * wv;
        a1 += nv[f][1] * wv;
        a2 += nv[f][2] * wv;
    }
    hs_bf[n * Fd + g] = f2bs(as);
    h_v[n * Fd * 3 + g * 3 + 0] = a0;
    h_v[n * Fd * 3 + g * 3 + 1] = a1;
    h_v[n * Fd * 3 + g * 3 + 2] = a2;
}

// ---------------------------------------------------------------------------
// Kernel 2: MFMA edge MLP + tensor products + atomic scatter.
// 256 threads = 4 waves, 64 edges/block, 16 edges/wave. No __syncthreads:
// each wave computes all columns for its own 16 edges; LDS rows are
// wave-private and LDS ops are in-order per wave.
// ---------------------------------------------------------------------------
__global__ __launch_bounds__(256, 2) void edge_kernel(
    const float* __restrict__ vectors, const float* __restrict__ lengths,
    const float* __restrict__ sef,
    const int* __restrict__ senders, const int* __restrict__ receivers,
    const float* __restrict__ b1f, const float* __restrict__ b2f,
    const float* __restrict__ b3f,
    const ushort_t* __restrict__ hs_bf, const float* __restrict__ h_v,
    const ushort_t* __restrict__ W1p, const ushort_t* __restrict__ W2p,
    const ushort_t* __restrict__ W3p,
    float* __restrict__ agg_s, float* __restrict__ agg_v)
{
    // H: 64 rows x 136 bf16 (stride 272B: 16B-aligned rows, 2-way-bank at worst)
    // Mix: 64 rows x 196 f32 (stride 784B)
    __shared__ ushort_t Hs[64 * 136];
    __shared__ float    Mix[64 * 196];

    const int tid  = threadIdx.x;
    const int wave = tid >> 6, lane = tid & 63;
    const int quad = lane >> 4, l4 = lane & 15;
    const int ebase = blockIdx.x * 64 + wave * 16;
    const int me    = ebase + l4;          // this lane's A-row edge
    const int hrow  = wave * 16;

    const int snd = senders[me];
    const int rcv = receivers[me];

    // ---- A-fragments for GEMM1: mlp_in[edge][k], K padded 161->192 ----
    bf16x8 a[6];
    a[0] = *(const bf16x8*)(hs_bf + snd * 64 + quad * 8);
    a[1] = *(const bf16x8*)(hs_bf + snd * 64 + 32 + quad * 8);
    a[2] = *(const bf16x8*)(hs_bf + rcv * 64 + quad * 8);
    a[3] = *(const bf16x8*)(hs_bf + rcv * 64 + 32 + quad * 8);
    {
        const float4 s0 = *(const float4*)(sef + (size_t)me * 32 + quad * 8);
        const float4 s1 = *(const float4*)(sef + (size_t)me * 32 + quad * 8 + 4);
        bf16x8 t;
        t[0] = (short)f2bs(s0.x); t[1] = (short)f2bs(s0.y);
        t[2] = (short)f2bs(s0.z); t[3] = (short)f2bs(s0.w);
        t[4] = (short)f2bs(s1.x); t[5] = (short)f2bs(s1.y);
        t[6] = (short)f2bs(s1.z); t[7] = (short)f2bs(s1.w);
        a[4] = t;
    }
    {
        bf16x8 t = {0, 0, 0, 0, 0, 0, 0, 0};
        if (quad == 0) t[0] = (short)f2bs(lengths[me]);
        a[5] = t;
    }

    const bf16x8* B1 = (const bf16x8*)W1p;
    const bf16x8* B2 = (const bf16x8*)W2p;
    const bf16x8* B3 = (const bf16x8*)W3p;

    // ---- GEMM1: 192(161) -> 128, silu ----
    f32x4 acc[12];
    #pragma unroll
    for (int t = 0; t < 8; t++) acc[t] = (f32x4){0.f, 0.f, 0.f, 0.f};
    #pragma unroll
    for (int c = 0; c < 6; c++) {
        #pragma unroll
        for (int t = 0; t < 8; t++)
            acc[t] = __builtin_amdgcn_mfma_f32_16x16x32_bf16(
                a[c], B1[(c * 8 + t) * 64 + lane], acc[t], 0, 0, 0);
    }
    // D layout: m = quad*4 + r (edge), n = t*16 + l4 (col)
    #pragma unroll
    for (int t = 0; t < 8; t++) {
        float bb = b1f[t * 16 + l4];
        #pragma unroll
        for (int r = 0; r < 4; r++) {
            float v = silu(acc[t][r] + bb);
            Hs[(hrow + quad * 4 + r) * 136 + t * 16 + l4] = f2bs(v);
        }
    }

    // ---- GEMM2: 128 -> 128, silu (A from Hs, own rows) ----
    #pragma unroll
    for (int t = 0; t < 8; t++) acc[t] = (f32x4){0.f, 0.f, 0.f, 0.f};
    #pragma unroll
    for (int c = 0; c < 4; c++) {
        bf16x8 af = *(const bf16x8*)(&Hs[(hrow + l4) * 136 + c * 32 + quad * 8]);
        #pragma unroll
        for (int t = 0; t < 8; t++)
            acc[t] = __builtin_amdgcn_mfma_f32_16x16x32_bf16(
                af, B2[(c * 8 + t) * 64 + lane], acc[t], 0, 0, 0);
    }
    #pragma unroll
    for (int t = 0; t < 8; t++) {
        float bb = b2f[t * 16 + l4];
        #pragma unroll
        for (int r = 0; r < 4; r++) {
            float v = silu(acc[t][r] + bb);
            Hs[(hrow + quad * 4 + r) * 136 + t * 16 + l4] = f2bs(v);
        }
    }

    // ---- GEMM3: 128 -> 192 (linear) ----
    f32x4 acc3[12];
    #pragma unroll
    for (int t = 0; t < 12; t++) acc3[t] = (f32x4){0.f, 0.f, 0.f, 0.f};
    #pragma unroll
    for (int c = 0; c < 4; c++) {
        bf16x8 af = *(const bf16x8*)(&Hs[(hrow + l4) * 136 + c * 32 + quad * 8]);
        #pragma unroll
        for (int t = 0; t < 12; t++)
            acc3[t] = __builtin_amdgcn_mfma_f32_16x16x32_bf16(
                af, B3[(c * 12 + t) * 64 + lane], acc3[t], 0, 0, 0);
    }
    #pragma unroll
    for (int t = 0; t < 12; t++) {
        float bb = b3f[t * 16 + l4];
        #pragma unroll
        for (int r = 0; r < 4; r++)
            Mix[(hrow + quad * 4 + r) * 196 + t * 16 + l4] = acc3[t][r] + bb;
    }

    // ---- epilogue: tensor products * mix, atomic scatter (already /16) ----
    const int f = lane;
    for (int e = 0; e < 16; e++) {
        const int ge = ebase + e;
        const int se = senders[ge];
        const int re = receivers[ge];
        const float ev0 = SQ3f * vectors[ge * 3 + 0];
        const float ev1 = SQ3f * vectors[ge * 3 + 1];
        const float ev2 = SQ3f * vectors[ge * 3 + 2];
        const float mv0 = h_v[(size_t)se * 192 + f * 3 + 0];
        const float mv1 = h_v[(size_t)se * 192 + f * 3 + 1];
        const float mv2 = h_v[(size_t)se * 192 + f * 3 + 2];
        const float m_s = bs2f(hs_bf[se * 64 + f]);
        const float* mrow = &Mix[(hrow + e) * 196];
        const float mixs = mrow[f];
        const float mix1 = mrow[64 + f];
        const float mix2 = mrow[128 + f];

        float tps = (mv0 * ev0 + mv1 * ev1 + mv2 * ev2) * INV_SQ3 * mixs * INV_AVG;
        atomicAdd(&agg_s[re * 64 + f], tps);

        float m1 = mix1 * INV_AVG;
        atomicAdd(&agg_v[(size_t)re * 384 + f * 3 + 0], m_s * ev0 * m1);
        atomicAdd(&agg_v[(size_t)re * 384 + f * 3 + 1], m_s * ev1 * m1);
        atomicAdd(&agg_v[(size_t)re * 384 + f * 3 + 2], m_s * ev2 * m1);

        float m2 = mix2 * INV_SQ2 * INV_AVG;
        float cx = mv1 * ev2 - mv2 * ev1;
        float cy = mv2 * ev0 - mv0 * ev2;
        float cz = mv0 * ev1 - mv1 * ev0;
        atomicAdd(&agg_v[(size_t)re * 384 + (64 + f) * 3 + 0], cx * m2);
        atomicAdd(&agg_v[(size_t)re * 384 + (64 + f) * 3 + 1], cy * m2);
        atomicAdd(&agg_v[(size_t)re * 384 + (64 + f) * 3 + 2], cz * m2);
    }
}

// ---------------------------------------------------------------------------
// Kernel 3: node-side tail (unchanged fp32 path). 64 thr / node.
// ---------------------------------------------------------------------------
__global__ __launch_bounds__(64) void node_kernel(
    const float* __restrict__ agg_s, const float* __restrict__ agg_v,
    const int* __restrict__ specie,
    const float* __restrict__ W_dn_s, const float* __restrict__ b_dn_s,
    const float* __restrict__ W_dn_v,
    const float* __restrict__ w_sc_s, const float* __restrict__ w_sc_v,
    const float* __restrict__ W_pb_s, const float* __restrict__ b_pb_s,
    const float* __restrict__ W_pb_v,
    const float* __restrict__ W_r1_s, const float* __restrict__ b_r1_s,
    const float* __restrict__ W_r1_v,
    const float* __restrict__ W_r2_s, const float* __restrict__ b_r2,
    const float* __restrict__ W_r2_v,
    float* __restrict__ out)
{
    __shared__ float as_l[Fd];
    __shared__ float av_l[2 * Fd][3];
    __shared__ float scs[Fd];
    __shared__ float scv[Fd][3];
    __shared__ float ps[Fd];
    __shared__ float pv[Fd][3];

    const int n = blockIdx.x;
    const int g = threadIdx.x;

    as_l[g] = agg_s[n * Fd + g];
    for (int idx = g; idx < 2 * Fd * 3; idx += 64)
        av_l[idx / 3][idx % 3] = agg_v[(size_t)n * (2 * Fd * 3) + idx];
    __syncthreads();

    float f_s = b_dn_s[g];
    #pragma unroll 8
    for (int f = 0; f < Fd; f++) f_s += as_l[f] * W_dn_s[f * Fd + g];
    float fv0 = 0.f, fv1 = 0.f, fv2 = 0.f;
    #pragma unroll 8
    for (int f = 0; f < 2 * Fd; f++) {
        float w = W_dn_v[f * Fd + g];
        fv0 += av_l[f][0] * w;
        fv1 += av_l[f][1] * w;
        fv2 += av_l[f][2] * w;
    }

    float vv = (fv0 * fv0 + fv1 * fv1 + fv2 * fv2) * INV_SQ3;
    int sp = specie[n];
    float ws0 = w_sc_s[sp * 3 * Fd + 0 * Fd + g];
    float ws1 = w_sc_s[sp * 3 * Fd + 1 * Fd + g];
    float ws2 = w_sc_s[sp * 3 * Fd + 2 * Fd + g];
    float wv0 = w_sc_v[sp * 2 * Fd + 0 * Fd + g];
    float wv1 = w_sc_v[sp * 2 * Fd + 1 * Fd + g];
    float sc_s = ws0 * f_s + ws1 * f_s * f_s + ws2 * vv;
    float kv = wv0 + wv1 * f_s;
    scs[g] = sc_s;
    scv[g][0] = kv * fv0;
    scv[g][1] = kv * fv1;
    scv[g][2] = kv * fv2;
    __syncthreads();

    float p_s = b_pb_s[g];
    float pv0 = 0.f, pv1 = 0.f, pv2 = 0.f;
    #pragma unroll 8
    for (int f = 0; f < Fd; f++) {
        float wps = W_pb_s[f * Fd + g];
        p_s += scs[f] * wps;
        float wpv = W_pb_v[f * Fd + g];
        pv0 += scv[f][0] * wpv;
        pv1 += scv[f][1] * wpv;
        pv2 += scv[f][2] * wpv;
    }
    ps[g] = p_s;
    pv[g][0] = pv0; pv[g][1] = pv1; pv[g][2] = pv2;

    out[OFF_PS + n * Fd + g] = p_s;
    out[OFF_PV + (size_t)n * Fd * 3 + g * 3 + 0] = pv0;
    out[OFF_PV + (size_t)n * Fd * 3 + g * 3 + 1] = pv1;
    out[OFF_PV + (size_t)n * Fd * 3 + g * 3 + 2] = pv2;
    __syncthreads();

    float r0 = b_r1_s[g];
    float r1 = b_r1_s[g + Fd];
    float rv0 = 0.f, rv1 = 0.f, rv2 = 0.f;
    #pragma unroll 8
    for (int f = 0; f < Fd; f++) {
        float p = ps[f];
        r0 += p * W_r1_s[f * 2 * Fd + g];
        r1 += p * W_r1_s[f * 2 * Fd + g + Fd];
        float wrv = W_r1_v[f * Fd + g];
        rv0 += pv[f][0] * wrv;
        rv1 += pv[f][1] * wrv;
        rv2 += pv[f][2] * wrv;
    }
    float act  = silu(r0);
    float gate = silu(r1);
    float o_s = act * W_r2_s[g];
    float wr2v = W_r2_v[g];
    float ov0 = gate * rv0 * wr2v;
    float ov1 = gate * rv1 * wr2v;
    float ov2 = gate * rv2 * wr2v;

    #pragma unroll
    for (int off = 32; off > 0; off >>= 1) {
        o_s += __shfl_down(o_s, off);
        ov0 += __shfl_down(ov0, off);
        ov1 += __shfl_down(ov1, off);
        ov2 += __shfl_down(ov2, off);
    }
    if (g == 0) {
        out[OFF_OS + n] = o_s + b_r2[0];
        out[OFF_OV + n * 3 + 0] = ov0;
        out[OFF_OV + n * 3 + 1] = ov1;
        out[OFF_OV + n * 3 + 2] = ov2;
    }
}

// ---------------------------------------------------------------------------
extern "C" void kernel_launch(void* const* d_in, const int* in_sizes, int n_in,
                              void* d_out, int out_size, void* d_ws, size_t ws_size,
                              hipStream_t stream)
{
    const float* vectors  = (const float*)d_in[0];
    const float* lengths  = (const float*)d_in[1];
    const float* node_s   = (const float*)d_in[2];
    const float* node_v   = (const float*)d_in[3];
    const float* sef      = (const float*)d_in[4];
    const int*  specie    = (const int*)d_in[5];
    const int*  senders   = (const int*)d_in[6];
    const int*  receivers = (const int*)d_in[7];
    const float* W_up_s   = (const float*)d_in[8];
    const float* b_up_s   = (const float*)d_in[9];
    const float* W_up_v   = (const float*)d_in[10];
    const float* mlp_W1   = (const float*)d_in[11];
    const float* mlp_b1   = (const float*)d_in[12];
    const float* mlp_W2   = (const float*)d_in[13];
    const float* mlp_b2   = (const float*)d_in[14];
    const float* mlp_W3   = (const float*)d_in[15];
    const float* mlp_b3   = (const float*)d_in[16];
    const float* W_dn_s   = (const float*)d_in[17];
    const float* b_dn_s   = (const float*)d_in[18];
    const float* W_dn_v   = (const float*)d_in[19];
    const float* w_sc_s   = (const float*)d_in[20];
    const float* w_sc_v   = (const float*)d_in[21];
    const float* W_pb_s   = (const float*)d_in[22];
    const float* b_pb_s   = (const float*)d_in[23];
    const float* W_pb_v   = (const float*)d_in[24];
    const float* W_r1_s   = (const float*)d_in[25];
    const float* b_r1_s   = (const float*)d_in[26];
    const float* W_r1_v   = (const float*)d_in[27];
    const float* W_r2_s   = (const float*)d_in[28];
    const float* b_r2     = (const float*)d_in[29];
    const float* W_r2_v   = (const float*)d_in[30];

    // ws layout: agg_s | agg_v | h_v (fp32) | hs_bf | W1p | W2p | W3p
    float* agg_s = (float*)d_ws;
    float* agg_v = agg_s + (size_t)N_ * Fd;
    float* h_v   = agg_v + (size_t)N_ * 2 * Fd * 3;
    ushort_t* hs_bf = (ushort_t*)(h_v + (size_t)N_ * Fd * 3);
    ushort_t* W1p = hs_bf + (size_t)N_ * Fd;
    ushort_t* W2p = W1p + W1P_SZ;
    ushort_t* W3p = W2p + W2P_SZ;

    float* out = (float*)d_out;

    hipMemsetAsync(agg_s, 0, (size_t)N_ * (Fd + 2 * Fd * 3) * sizeof(float), stream);

    pack_kernel<<<256, 256, 0, stream>>>(mlp_W1, mlp_W2, mlp_W3, W1p, W2p, W3p);

    up_kernel<<<N_, 64, 0, stream>>>(node_s, node_v, W_up_s, b_up_s, W_up_v,
                                     hs_bf, h_v);

    edge_kernel<<<E_ / 64, 256, 0, stream>>>(
        vectors, lengths, sef, senders, receivers,
        mlp_b1, mlp_b2, mlp_b3,
        hs_bf, h_v, W1p, W2p, W3p, agg_s, agg_v);

    node_kernel<<<N_, 64, 0, stream>>>(
        agg_s, agg_v, specie,
        W_dn_s, b_dn_s, W_dn_v, w_sc_s, w_sc_v,
        W_pb_s, b_pb_s, W_pb_v, W_r1_s, b_r1_s, W_r1_v,
        W_r2_s, b_r2, W_r2_v, out);
}

// Round 4
// 452.359 us; speedup vs baseline: 3.0753x; 2.8005x over previous
//
#include <hip/hip_runtime.h>

typedef short bf16x8 __attribute__((ext_vector_type(8)));
typedef float f32x4  __attribute__((ext_vector_type(4)));
typedef unsigned short ushort_t;

__device__ __forceinline__ float silu(float x) { return x / (1.0f + __expf(-x)); }

__device__ __forceinline__ ushort_t f2bs(float x) {
    union { float f; unsigned int u; } v; v.f = x;
    unsigned int r = v.u + 0x7FFF + ((v.u >> 16) & 1);
    return (ushort_t)(r >> 16);
}
__device__ __forceinline__ float bs2f(ushort_t x) {
    union { unsigned int u; float f; } v; v.u = ((unsigned int)x) << 16; return v.f;
}

constexpr int N_   = 16000;
constexpr int E_   = 256000;
constexpr int Fd   = 64;

constexpr float SQ3f    = 1.7320508075688772f;
constexpr float INV_SQ3 = 0.5773502691896258f;
constexpr float INV_SQ2 = 0.7071067811865476f;
constexpr float INV_AVG = 0.0625f;  // 1/16

// output layout (flat): out_s | out_v | p_s | p_v
constexpr int OFF_OS = 0;
constexpr int OFF_OV = N_;
constexpr int OFF_PS = OFF_OV + 3 * N_;
constexpr int OFF_PV = OFF_PS + N_ * Fd;

// packed-weight region sizes (ushorts)
constexpr int W1P_SZ = 6 * 8 * 512;
constexpr int W2P_SZ = 4 * 8 * 512;
constexpr int W3P_SZ = 4 * 12 * 512;

// ---------------------------------------------------------------------------
// pack weights fp32 -> bf16 MFMA B-fragment order
// ---------------------------------------------------------------------------
__global__ __launch_bounds__(256) void pack_kernel(
    const float* __restrict__ W1, const float* __restrict__ W2,
    const float* __restrict__ W3,
    ushort_t* __restrict__ W1p, ushort_t* __restrict__ W2p,
    ushort_t* __restrict__ W3p)
{
    int idx = blockIdx.x * 256 + threadIdx.x;  // 65536 total
    if (idx < W1P_SZ) {
        int j = idx & 7, lane = (idx >> 3) & 63, tile = idx >> 9;
        int c = tile >> 3, t = tile & 7;
        int k = c * 32 + (lane >> 4) * 8 + j;
        int n = t * 16 + (lane & 15);
        W1p[idx] = f2bs(k < 161 ? W1[k * 128 + n] : 0.f);
    } else if (idx < W1P_SZ + W2P_SZ) {
        int q = idx - W1P_SZ;
        int j = q & 7, lane = (q >> 3) & 63, tile = q >> 9;
        int c = tile >> 3, t = tile & 7;
        int k = c * 32 + (lane >> 4) * 8 + j;
        int n = t * 16 + (lane & 15);
        W2p[q] = f2bs(W2[k * 128 + n]);
    } else {
        int q = idx - W1P_SZ - W2P_SZ;
        int j = q & 7, lane = (q >> 3) & 63, tile = q >> 9;
        int c = tile / 12, t = tile % 12;
        int k = c * 32 + (lane >> 4) * 8 + j;
        int n = t * 16 + (lane & 15);
        W3p[q] = f2bs(W3[k * 192 + n]);
    }
}

// ---------------------------------------------------------------------------
// Kernel 1: node up-projection. h_s as bf16, h_v fp32.
// ---------------------------------------------------------------------------
__global__ __launch_bounds__(64) void up_kernel(
    const float* __restrict__ node_s, const float* __restrict__ node_v,
    const float* __restrict__ W_up_s, const float* __restrict__ b_up_s,
    const float* __restrict__ W_up_v,
    ushort_t* __restrict__ hs_bf, float* __restrict__ h_v)
{
    __shared__ float ns[Fd];
    __shared__ float nv[Fd][3];
    const int n = blockIdx.x;
    const int g = threadIdx.x;

    ns[g] = node_s[n * Fd + g];
    for (int idx = g; idx < Fd * 3; idx += 64)
        nv[idx / 3][idx % 3] = node_v[n * Fd * 3 + idx];
    __syncthreads();

    float as = b_up_s[g];
    float a0 = 0.f, a1 = 0.f, a2 = 0.f;
    #pragma unroll 8
    for (int f = 0; f < Fd; f++) {
        float wss = W_up_s[f * Fd + g];
        as += ns[f] * wss;
        float wv = W_up_v[f * Fd + g];
        a0 += nv[f][0] * wv;
        a1 += nv[f][1] * wv;
        a2 += nv[f][2] * wv;
    }
    hs_bf[n * Fd + g] = f2bs(as);
    h_v[n * Fd * 3 + g * 3 + 0] = a0;
    h_v[n * Fd * 3 + g * 3 + 1] = a1;
    h_v[n * Fd * 3 + g * 3 + 2] = a2;
}

// ---------------------------------------------------------------------------
// CSR build: count -> scan -> scatter
// ---------------------------------------------------------------------------
__global__ __launch_bounds__(256) void count_kernel(
    const int* __restrict__ receivers, int* __restrict__ cnt)
{
    int e = blockIdx.x * 256 + threadIdx.x;
    if (e < E_) atomicAdd(&cnt[receivers[e]], 1);
}

__global__ __launch_bounds__(1024) void scan_kernel(
    const int* __restrict__ cnt, int* __restrict__ base, int* __restrict__ cursor)
{
    __shared__ int part[1024];
    const int t = threadIdx.x;
    const int i0 = t * 16;
    int s = 0;
    #pragma unroll
    for (int i = 0; i < 16; i++) {
        int idx = i0 + i;
        if (idx < N_) s += cnt[idx];
    }
    part[t] = s;
    __syncthreads();
    for (int off = 1; off < 1024; off <<= 1) {
        int v = (t >= off) ? part[t - off] : 0;
        __syncthreads();
        part[t] += v;
        __syncthreads();
    }
    int run = part[t] - s;  // exclusive prefix
    #pragma unroll
    for (int i = 0; i < 16; i++) {
        int idx = i0 + i;
        if (idx < N_) {
            base[idx] = run;
            cursor[idx] = run;
            run += cnt[idx];
        }
    }
}

__global__ __launch_bounds__(256) void scatter_kernel(
    const int* __restrict__ receivers, int* __restrict__ cursor,
    int* __restrict__ sorted_eid)
{
    int e = blockIdx.x * 256 + threadIdx.x;
    if (e < E_) {
        int p = atomicAdd(&cursor[receivers[e]], 1);
        sorted_eid[p] = e;
    }
}

// ---------------------------------------------------------------------------
// Kernel 2: MFMA edge MLP. Stores mix rows (192 bf16/edge), no atomics.
// 256 threads = 4 waves, 64 edges/block, 16 edges/wave, no __syncthreads.
// ---------------------------------------------------------------------------
__global__ __launch_bounds__(256, 4) void edge_mlp_kernel(
    const float* __restrict__ lengths, const float* __restrict__ sef,
    const int* __restrict__ senders, const int* __restrict__ receivers,
    const float* __restrict__ b1f, const float* __restrict__ b2f,
    const float* __restrict__ b3f,
    const ushort_t* __restrict__ hs_bf,
    const ushort_t* __restrict__ W1p, const ushort_t* __restrict__ W2p,
    const ushort_t* __restrict__ W3p,
    ushort_t* __restrict__ tpx)
{
    __shared__ ushort_t Hs[64 * 136];   // 17.4 KB

    const int tid  = threadIdx.x;
    const int wave = tid >> 6, lane = tid & 63;
    const int quad = lane >> 4, l4 = lane & 15;
    const int ebase = blockIdx.x * 64 + wave * 16;
    const int me    = ebase + l4;
    const int hrow  = wave * 16;

    const int snd = senders[me];
    const int rcv = receivers[me];

    bf16x8 a[6];
    a[0] = *(const bf16x8*)(hs_bf + snd * 64 + quad * 8);
    a[1] = *(const bf16x8*)(hs_bf + snd * 64 + 32 + quad * 8);
    a[2] = *(const bf16x8*)(hs_bf + rcv * 64 + quad * 8);
    a[3] = *(const bf16x8*)(hs_bf + rcv * 64 + 32 + quad * 8);
    {
        const float4 s0 = *(const float4*)(sef + (size_t)me * 32 + quad * 8);
        const float4 s1 = *(const float4*)(sef + (size_t)me * 32 + quad * 8 + 4);
        bf16x8 t;
        t[0] = (short)f2bs(s0.x); t[1] = (short)f2bs(s0.y);
        t[2] = (short)f2bs(s0.z); t[3] = (short)f2bs(s0.w);
        t[4] = (short)f2bs(s1.x); t[5] = (short)f2bs(s1.y);
        t[6] = (short)f2bs(s1.z); t[7] = (short)f2bs(s1.w);
        a[4] = t;
    }
    {
        bf16x8 t = {0, 0, 0, 0, 0, 0, 0, 0};
        if (quad == 0) t[0] = (short)f2bs(lengths[me]);
        a[5] = t;
    }

    const bf16x8* B1 = (const bf16x8*)W1p;
    const bf16x8* B2 = (const bf16x8*)W2p;
    const bf16x8* B3 = (const bf16x8*)W3p;

    // GEMM1: 192(161) -> 128, silu
    f32x4 acc[8];
    #pragma unroll
    for (int t = 0; t < 8; t++) acc[t] = (f32x4){0.f, 0.f, 0.f, 0.f};
    #pragma unroll
    for (int c = 0; c < 6; c++) {
        #pragma unroll
        for (int t = 0; t < 8; t++)
            acc[t] = __builtin_amdgcn_mfma_f32_16x16x32_bf16(
                a[c], B1[(c * 8 + t) * 64 + lane], acc[t], 0, 0, 0);
    }
    #pragma unroll
    for (int t = 0; t < 8; t++) {
        float bb = b1f[t * 16 + l4];
        #pragma unroll
        for (int r = 0; r < 4; r++)
            Hs[(hrow + quad * 4 + r) * 136 + t * 16 + l4] = f2bs(silu(acc[t][r] + bb));
    }

    // GEMM2: 128 -> 128, silu
    #pragma unroll
    for (int t = 0; t < 8; t++) acc[t] = (f32x4){0.f, 0.f, 0.f, 0.f};
    #pragma unroll
    for (int c = 0; c < 4; c++) {
        bf16x8 af = *(const bf16x8*)(&Hs[(hrow + l4) * 136 + c * 32 + quad * 8]);
        #pragma unroll
        for (int t = 0; t < 8; t++)
            acc[t] = __builtin_amdgcn_mfma_f32_16x16x32_bf16(
                af, B2[(c * 8 + t) * 64 + lane], acc[t], 0, 0, 0);
    }
    #pragma unroll
    for (int t = 0; t < 8; t++) {
        float bb = b2f[t * 16 + l4];
        #pragma unroll
        for (int r = 0; r < 4; r++)
            Hs[(hrow + quad * 4 + r) * 136 + t * 16 + l4] = f2bs(silu(acc[t][r] + bb));
    }

    // GEMM3: 128 -> 192, store mix row straight to global (bf16)
    f32x4 acc3[12];
    #pragma unroll
    for (int t = 0; t < 12; t++) acc3[t] = (f32x4){0.f, 0.f, 0.f, 0.f};
    #pragma unroll
    for (int c = 0; c < 4; c++) {
        bf16x8 af = *(const bf16x8*)(&Hs[(hrow + l4) * 136 + c * 32 + quad * 8]);
        #pragma unroll
        for (int t = 0; t < 12; t++)
            acc3[t] = __builtin_amdgcn_mfma_f32_16x16x32_bf16(
                af, B3[(c * 12 + t) * 64 + lane], acc3[t], 0, 0, 0);
    }
    #pragma unroll
    for (int t = 0; t < 12; t++) {
        float bb = b3f[t * 16 + l4];
        #pragma unroll
        for (int r = 0; r < 4; r++)
            tpx[(size_t)(ebase + quad * 4 + r) * 192 + t * 16 + l4] =
                f2bs(acc3[t][r] + bb);
    }
}

// ---------------------------------------------------------------------------
// Kernel 3: fused CSR aggregation + node tail. One 64-thread block per node.
// ---------------------------------------------------------------------------
__global__ __launch_bounds__(64) void node_fused_kernel(
    const int* __restrict__ base, const int* __restrict__ cnt,
    const int* __restrict__ sorted_eid, const int* __restrict__ senders,
    const float* __restrict__ vectors,
    const ushort_t* __restrict__ tpx,
    const ushort_t* __restrict__ hs_bf, const float* __restrict__ h_v,
    const int* __restrict__ specie,
    const float* __restrict__ W_dn_s, const float* __restrict__ b_dn_s,
    const float* __restrict__ W_dn_v,
    const float* __restrict__ w_sc_s, const float* __restrict__ w_sc_v,
    const float* __restrict__ W_pb_s, const float* __restrict__ b_pb_s,
    const float* __restrict__ W_pb_v,
    const float* __restrict__ W_r1_s, const float* __restrict__ b_r1_s,
    const float* __restrict__ W_r1_v,
    const float* __restrict__ W_r2_s, const float* __restrict__ b_r2,
    const float* __restrict__ W_r2_v,
    float* __restrict__ out)
{
    __shared__ float as_l[Fd];
    __shared__ float av_l[2 * Fd][3];
    __shared__ float scs[Fd];
    __shared__ float scv[Fd][3];
    __shared__ float ps[Fd];
    __shared__ float pv[Fd][3];
    __shared__ int   eids[64];

    const int n = blockIdx.x;
    const int g = threadIdx.x;  // = f

    // ---- CSR aggregation ----
    const int b = base[n];
    const int c = cnt[n];
    float accS = 0.f;
    float a10 = 0.f, a11 = 0.f, a12 = 0.f;
    float a20 = 0.f, a21 = 0.f, a22 = 0.f;

    for (int done = 0; done < c; done += 64) {
        int m = min(64, c - done);
        __syncthreads();
        if (g < m) eids[g] = sorted_eid[b + done + g];
        __syncthreads();
        for (int i = 0; i < m; i++) {
            const int e  = eids[i];
            const int se = senders[e];
            const float ev0 = SQ3f * vectors[e * 3 + 0];
            const float ev1 = SQ3f * vectors[e * 3 + 1];
            const float ev2 = SQ3f * vectors[e * 3 + 2];
            const float mv0 = h_v[(size_t)se * 192 + g * 3 + 0];
            const float mv1 = h_v[(size_t)se * 192 + g * 3 + 1];
            const float mv2 = h_v[(size_t)se * 192 + g * 3 + 2];
            const float m_s = bs2f(hs_bf[se * 64 + g]);
            const ushort_t* mrow = tpx + (size_t)e * 192;
            const float c0 = bs2f(mrow[g]);
            const float c1 = bs2f(mrow[64 + g]);
            const float c2 = bs2f(mrow[128 + g]);

            float dot = mv0 * ev0 + mv1 * ev1 + mv2 * ev2;
            accS += dot * c0;
            float k1 = m_s * c1;
            a10 += k1 * ev0; a11 += k1 * ev1; a12 += k1 * ev2;
            a20 += (mv1 * ev2 - mv2 * ev1) * c2;
            a21 += (mv2 * ev0 - mv0 * ev2) * c2;
            a22 += (mv0 * ev1 - mv1 * ev0) * c2;
        }
    }
    as_l[g] = accS * (INV_SQ3 * INV_AVG);
    av_l[g][0] = a10 * INV_AVG;
    av_l[g][1] = a11 * INV_AVG;
    av_l[g][2] = a12 * INV_AVG;
    av_l[64 + g][0] = a20 * (INV_SQ2 * INV_AVG);
    av_l[64 + g][1] = a21 * (INV_SQ2 * INV_AVG);
    av_l[64 + g][2] = a22 * (INV_SQ2 * INV_AVG);
    __syncthreads();

    // ---- node tail ----
    float f_s = b_dn_s[g];
    #pragma unroll 8
    for (int f = 0; f < Fd; f++) f_s += as_l[f] * W_dn_s[f * Fd + g];
    float fv0 = 0.f, fv1 = 0.f, fv2 = 0.f;
    #pragma unroll 8
    for (int f = 0; f < 2 * Fd; f++) {
        float w = W_dn_v[f * Fd + g];
        fv0 += av_l[f][0] * w;
        fv1 += av_l[f][1] * w;
        fv2 += av_l[f][2] * w;
    }

    float vv = (fv0 * fv0 + fv1 * fv1 + fv2 * fv2) * INV_SQ3;
    int sp = specie[n];
    float ws0 = w_sc_s[sp * 3 * Fd + 0 * Fd + g];
    float ws1 = w_sc_s[sp * 3 * Fd + 1 * Fd + g];
    float ws2 = w_sc_s[sp * 3 * Fd + 2 * Fd + g];
    float wv0 = w_sc_v[sp * 2 * Fd + 0 * Fd + g];
    float wv1 = w_sc_v[sp * 2 * Fd + 1 * Fd + g];
    float sc_s = ws0 * f_s + ws1 * f_s * f_s + ws2 * vv;
    float kv = wv0 + wv1 * f_s;
    scs[g] = sc_s;
    scv[g][0] = kv * fv0;
    scv[g][1] = kv * fv1;
    scv[g][2] = kv * fv2;
    __syncthreads();

    float p_s = b_pb_s[g];
    float pv0 = 0.f, pv1 = 0.f, pv2 = 0.f;
    #pragma unroll 8
    for (int f = 0; f < Fd; f++) {
        float wps = W_pb_s[f * Fd + g];
        p_s += scs[f] * wps;
        float wpv = W_pb_v[f * Fd + g];
        pv0 += scv[f][0] * wpv;
        pv1 += scv[f][1] * wpv;
        pv2 += scv[f][2] * wpv;
    }
    ps[g] = p_s;
    pv[g][0] = pv0; pv[g][1] = pv1; pv[g][2] = pv2;

    out[OFF_PS + n * Fd + g] = p_s;
    out[OFF_PV + (size_t)n * Fd * 3 + g * 3 + 0] = pv0;
    out[OFF_PV + (size_t)n * Fd * 3 + g * 3 + 1] = pv1;
    out[OFF_PV + (size_t)n * Fd * 3 + g * 3 + 2] = pv2;
    __syncthreads();

    float r0 = b_r1_s[g];
    float r1 = b_r1_s[g + Fd];
    float rv0 = 0.f, rv1 = 0.f, rv2 = 0.f;
    #pragma unroll 8
    for (int f = 0; f < Fd; f++) {
        float p = ps[f];
        r0 += p * W_r1_s[f * 2 * Fd + g];
        r1 += p * W_r1_s[f * 2 * Fd + g + Fd];
        float wrv = W_r1_v[f * Fd + g];
        rv0 += pv[f][0] * wrv;
        rv1 += pv[f][1] * wrv;
        rv2 += pv[f][2] * wrv;
    }
    float act  = silu(r0);
    float gate = silu(r1);
    float o_s = act * W_r2_s[g];
    float wr2v = W_r2_v[g];
    float ov0 = gate * rv0 * wr2v;
    float ov1 = gate * rv1 * wr2v;
    float ov2 = gate * rv2 * wr2v;

    #pragma unroll
    for (int off = 32; off > 0; off >>= 1) {
        o_s += __shfl_down(o_s, off);
        ov0 += __shfl_down(ov0, off);
        ov1 += __shfl_down(ov1, off);
        ov2 += __shfl_down(ov2, off);
    }
    if (g == 0) {
        out[OFF_OS + n] = o_s + b_r2[0];
        out[OFF_OV + n * 3 + 0] = ov0;
        out[OFF_OV + n * 3 + 1] = ov1;
        out[OFF_OV + n * 3 + 2] = ov2;
    }
}

// ---------------------------------------------------------------------------
extern "C" void kernel_launch(void* const* d_in, const int* in_sizes, int n_in,
                              void* d_out, int out_size, void* d_ws, size_t ws_size,
                              hipStream_t stream)
{
    const float* vectors  = (const float*)d_in[0];
    const float* lengths  = (const float*)d_in[1];
    const float* node_s   = (const float*)d_in[2];
    const float* node_v   = (const float*)d_in[3];
    const float* sef      = (const float*)d_in[4];
    const int*  specie    = (const int*)d_in[5];
    const int*  senders   = (const int*)d_in[6];
    const int*  receivers = (const int*)d_in[7];
    const float* W_up_s   = (const float*)d_in[8];
    const float* b_up_s   = (const float*)d_in[9];
    const float* W_up_v   = (const float*)d_in[10];
    const float* mlp_W1   = (const float*)d_in[11];
    const float* mlp_b1   = (const float*)d_in[12];
    const float* mlp_W2   = (const float*)d_in[13];
    const float* mlp_b2   = (const float*)d_in[14];
    const float* mlp_W3   = (const float*)d_in[15];
    const float* mlp_b3   = (const float*)d_in[16];
    const float* W_dn_s   = (const float*)d_in[17];
    const float* b_dn_s   = (const float*)d_in[18];
    const float* W_dn_v   = (const float*)d_in[19];
    const float* w_sc_s   = (const float*)d_in[20];
    const float* w_sc_v   = (const float*)d_in[21];
    const float* W_pb_s   = (const float*)d_in[22];
    const float* b_pb_s   = (const float*)d_in[23];
    const float* W_pb_v   = (const float*)d_in[24];
    const float* W_r1_s   = (const float*)d_in[25];
    const float* b_r1_s   = (const float*)d_in[26];
    const float* W_r1_v   = (const float*)d_in[27];
    const float* W_r2_s   = (const float*)d_in[28];
    const float* b_r2     = (const float*)d_in[29];
    const float* W_r2_v   = (const float*)d_in[30];

    // ws layout: h_v(f32) | tpx(u16) | hs_bf(u16) | Wpacks(u16) | ints
    float* h_v = (float*)d_ws;                                   // N*192 f32
    ushort_t* tpx   = (ushort_t*)(h_v + (size_t)N_ * 192);       // E*192 u16
    ushort_t* hs_bf = tpx + (size_t)E_ * 192;                    // N*64 u16
    ushort_t* W1p   = hs_bf + (size_t)N_ * 64;
    ushort_t* W2p   = W1p + W1P_SZ;
    ushort_t* W3p   = W2p + W2P_SZ;
    int* cnt        = (int*)(W3p + W3P_SZ + (((size_t)(W3p + W3P_SZ)) & 1 ? 1 : 0));
    // ensure 4-byte alignment (u16 counts so far are even; keep simple)
    cnt = (int*)((((size_t)(W3p + W3P_SZ)) + 3) & ~(size_t)3);
    int* base       = cnt + N_;
    int* cursor     = base + N_;
    int* sorted_eid = cursor + N_;                               // E ints

    float* out = (float*)d_out;

    hipMemsetAsync(cnt, 0, N_ * sizeof(int), stream);

    count_kernel<<<(E_ + 255) / 256, 256, 0, stream>>>(receivers, cnt);
    pack_kernel<<<256, 256, 0, stream>>>(mlp_W1, mlp_W2, mlp_W3, W1p, W2p, W3p);
    up_kernel<<<N_, 64, 0, stream>>>(node_s, node_v, W_up_s, b_up_s, W_up_v,
                                     hs_bf, h_v);
    scan_kernel<<<1, 1024, 0, stream>>>(cnt, base, cursor);
    scatter_kernel<<<(E_ + 255) / 256, 256, 0, stream>>>(receivers, cursor,
                                                         sorted_eid);
    edge_mlp_kernel<<<E_ / 64, 256, 0, stream>>>(
        lengths, sef, senders, receivers,
        mlp_b1, mlp_b2, mlp_b3,
        hs_bf, W1p, W2p, W3p, tpx);

    node_fused_kernel<<<N_, 64, 0, stream>>>(
        base, cnt, sorted_eid, senders, vectors,
        tpx, hs_bf, h_v, specie,
        W_dn_s, b_dn_s, W_dn_v, w_sc_s, w_sc_v,
        W_pb_s, b_pb_s, W_pb_v, W_r1_s, b_r1_s, W_r1_v,
        W_r2_s, b_r2, W_r2_v, out);
}

// Round 5
// 413.603 us; speedup vs baseline: 3.3635x; 1.0937x over previous
//
#include <hip/hip_runtime.h>

typedef short bf16x8 __attribute__((ext_vector_type(8)));
typedef float f32x4  __attribute__((ext_vector_type(4)));
typedef unsigned short ushort_t;

// fast silu: x * rcp(1+exp(-x)) — rcp is v_rcp_f32 (1 op, ~1e-7 rel err)
__device__ __forceinline__ float silu(float x) {
    float t = __expf(-x);
    return x * __builtin_amdgcn_rcpf(1.f + t);
}

// RNE float -> bf16 bits (used for final tpx only)
__device__ __forceinline__ ushort_t f2bs(float x) {
    union { float f; unsigned int u; } v; v.f = x;
    unsigned int r = v.u + 0x7FFF + ((v.u >> 16) & 1);
    return (ushort_t)(r >> 16);
}
// truncating float -> bf16 bits (1 op; for LDS intermediates)
__device__ __forceinline__ ushort_t f2bs_t(float x) {
    union { float f; unsigned int u; } v; v.f = x;
    return (ushort_t)(v.u >> 16);
}
__device__ __forceinline__ float bs2f(ushort_t x) {
    union { unsigned int u; float f; } v; v.u = ((unsigned int)x) << 16; return v.f;
}

constexpr int N_   = 16000;
constexpr int E_   = 256000;
constexpr int Fd   = 64;

constexpr float SQ3f    = 1.7320508075688772f;
constexpr float INV_SQ3 = 0.5773502691896258f;
constexpr float INV_SQ2 = 0.7071067811865476f;
constexpr float INV_AVG = 0.0625f;  // 1/16

// output layout (flat): out_s | out_v | p_s | p_v
constexpr int OFF_OS = 0;
constexpr int OFF_OV = N_;
constexpr int OFF_PS = OFF_OV + 3 * N_;
constexpr int OFF_PV = OFF_PS + N_ * Fd;

// packed-weight region sizes (ushorts)
constexpr int W1P_SZ = 6 * 8 * 512;
constexpr int W2P_SZ = 4 * 8 * 512;
constexpr int W3P_SZ = 4 * 12 * 512;

// ---------------------------------------------------------------------------
// pack weights fp32 -> bf16 MFMA B-fragment order
// B-frag: lane l holds B[k = c*32 + (l>>4)*8 + j][n = t*16 + (l&15)], j=0..7
// ---------------------------------------------------------------------------
__global__ __launch_bounds__(256) void pack_kernel(
    const float* __restrict__ W1, const float* __restrict__ W2,
    const float* __restrict__ W3,
    ushort_t* __restrict__ W1p, ushort_t* __restrict__ W2p,
    ushort_t* __restrict__ W3p)
{
    int idx = blockIdx.x * 256 + threadIdx.x;  // 65536 total
    if (idx < W1P_SZ) {
        int j = idx & 7, lane = (idx >> 3) & 63, tile = idx >> 9;
        int c = tile >> 3, t = tile & 7;
        int k = c * 32 + (lane >> 4) * 8 + j;
        int n = t * 16 + (lane & 15);
        W1p[idx] = f2bs(k < 161 ? W1[k * 128 + n] : 0.f);
    } else if (idx < W1P_SZ + W2P_SZ) {
        int q = idx - W1P_SZ;
        int j = q & 7, lane = (q >> 3) & 63, tile = q >> 9;
        int c = tile >> 3, t = tile & 7;
        int k = c * 32 + (lane >> 4) * 8 + j;
        int n = t * 16 + (lane & 15);
        W2p[q] = f2bs(W2[k * 128 + n]);
    } else {
        int q = idx - W1P_SZ - W2P_SZ;
        int j = q & 7, lane = (q >> 3) & 63, tile = q >> 9;
        int c = tile / 12, t = tile % 12;
        int k = c * 32 + (lane >> 4) * 8 + j;
        int n = t * 16 + (lane & 15);
        W3p[q] = f2bs(W3[k * 192 + n]);
    }
}

// ---------------------------------------------------------------------------
// Kernel 1: node up-projection + fused receiver-count.
// h_s as bf16; h_v fp32 SoA: h_v[n*192 + c*64 + g].
// Block n also counts receivers of edges [n*16, n*16+16)  (E = 16*N).
// ---------------------------------------------------------------------------
__global__ __launch_bounds__(64) void up_kernel(
    const float* __restrict__ node_s, const float* __restrict__ node_v,
    const float* __restrict__ W_up_s, const float* __restrict__ b_up_s,
    const float* __restrict__ W_up_v,
    const int* __restrict__ receivers, int* __restrict__ cnt,
    ushort_t* __restrict__ hs_bf, float* __restrict__ h_v)
{
    __shared__ float ns[Fd];
    __shared__ float nv[Fd][3];
    const int n = blockIdx.x;
    const int g = threadIdx.x;

    if (g < 16) {
        int e = n * 16 + g;
        atomicAdd(&cnt[receivers[e]], 1);
    }

    ns[g] = node_s[n * Fd + g];
    for (int idx = g; idx < Fd * 3; idx += 64)
        nv[idx / 3][idx % 3] = node_v[n * Fd * 3 + idx];
    __syncthreads();

    float as = b_up_s[g];
    float a0 = 0.f, a1 = 0.f, a2 = 0.f;
    #pragma unroll 8
    for (int f = 0; f < Fd; f++) {
        float wss = W_up_s[f * Fd + g];
        as += ns[f] * wss;
        float wv = W_up_v[f * Fd + g];
        a0 += nv[f][0] * wv;
        a1 += nv[f][1] * wv;
        a2 += nv[f][2] * wv;
    }
    hs_bf[n * Fd + g] = f2bs(as);
    h_v[n * 192 + 0 * 64 + g] = a0;
    h_v[n * 192 + 1 * 64 + g] = a1;
    h_v[n * 192 + 2 * 64 + g] = a2;
}

// ---------------------------------------------------------------------------
// CSR scan: 1000 active threads x 16 nodes, int4-vectorized
// ---------------------------------------------------------------------------
__global__ __launch_bounds__(1024) void scan_kernel(
    const int* __restrict__ cnt, int* __restrict__ base, int* __restrict__ cursor)
{
    __shared__ int part[1024];
    const int t = threadIdx.x;
    int v[16];
    int s = 0;
    if (t < 1000) {
        const int4* c4 = (const int4*)(cnt + t * 16);
        #pragma unroll
        for (int q = 0; q < 4; q++) {
            int4 w = c4[q];
            v[q * 4 + 0] = w.x; v[q * 4 + 1] = w.y;
            v[q * 4 + 2] = w.z; v[q * 4 + 3] = w.w;
            s += w.x + w.y + w.z + w.w;
        }
    }
    part[t] = s;
    __syncthreads();
    for (int off = 1; off < 1024; off <<= 1) {
        int u = (t >= off) ? part[t - off] : 0;
        __syncthreads();
        part[t] += u;
        __syncthreads();
    }
    if (t < 1000) {
        int run = part[t] - s;  // exclusive prefix
        int b[16];
        #pragma unroll
        for (int i = 0; i < 16; i++) { b[i] = run; run += v[i]; }
        int4* bb = (int4*)(base + t * 16);
        int4* cc = (int4*)(cursor + t * 16);
        #pragma unroll
        for (int q = 0; q < 4; q++) {
            int4 w = { b[q * 4], b[q * 4 + 1], b[q * 4 + 2], b[q * 4 + 3] };
            bb[q] = w;
            cc[q] = w;
        }
    }
}

// ---------------------------------------------------------------------------
// Kernel 2: MFMA edge MLP + fused CSR scatter. Stores mix rows (192 bf16/edge).
// 256 threads = 4 waves, 64 edges/block, 16 edges/wave, no __syncthreads.
// ---------------------------------------------------------------------------
__global__ __launch_bounds__(256, 6) void edge_mlp_kernel(
    const float* __restrict__ lengths, const float* __restrict__ sef,
    const int* __restrict__ senders, const int* __restrict__ receivers,
    const float* __restrict__ b1f, const float* __restrict__ b2f,
    const float* __restrict__ b3f,
    const ushort_t* __restrict__ hs_bf,
    const ushort_t* __restrict__ W1p, const ushort_t* __restrict__ W2p,
    const ushort_t* __restrict__ W3p,
    int* __restrict__ cursor, int* __restrict__ sorted_eid,
    ushort_t* __restrict__ tpx)
{
    __shared__ ushort_t Hs[64 * 136];   // 17.4 KB

    const int tid  = threadIdx.x;
    const int wave = tid >> 6, lane = tid & 63;
    const int quad = lane >> 4, l4 = lane & 15;
    const int ebase = blockIdx.x * 64 + wave * 16;
    const int me    = ebase + l4;
    const int hrow  = wave * 16;

    // fused CSR scatter for this block's 64 edges (result consumed next kernel)
    if (tid < 64) {
        int e = blockIdx.x * 64 + tid;
        int p = atomicAdd(&cursor[receivers[e]], 1);
        sorted_eid[p] = e;
    }

    const int snd = senders[me];
    const int rcv = receivers[me];

    bf16x8 a[6];
    a[0] = *(const bf16x8*)(hs_bf + snd * 64 + quad * 8);
    a[1] = *(const bf16x8*)(hs_bf + snd * 64 + 32 + quad * 8);
    a[2] = *(const bf16x8*)(hs_bf + rcv * 64 + quad * 8);
    a[3] = *(const bf16x8*)(hs_bf + rcv * 64 + 32 + quad * 8);
    {
        const float4 s0 = *(const float4*)(sef + (size_t)me * 32 + quad * 8);
        const float4 s1 = *(const float4*)(sef + (size_t)me * 32 + quad * 8 + 4);
        bf16x8 t;
        t[0] = (short)f2bs(s0.x); t[1] = (short)f2bs(s0.y);
        t[2] = (short)f2bs(s0.z); t[3] = (short)f2bs(s0.w);
        t[4] = (short)f2bs(s1.x); t[5] = (short)f2bs(s1.y);
        t[6] = (short)f2bs(s1.z); t[7] = (short)f2bs(s1.w);
        a[4] = t;
    }
    {
        bf16x8 t = {0, 0, 0, 0, 0, 0, 0, 0};
        if (quad == 0) t[0] = (short)f2bs(lengths[me]);
        a[5] = t;
    }

    const bf16x8* B1 = (const bf16x8*)W1p;
    const bf16x8* B2 = (const bf16x8*)W2p;
    const bf16x8* B3 = (const bf16x8*)W3p;

    // GEMM1: 192(161) -> 128, silu
    f32x4 acc[8];
    #pragma unroll
    for (int t = 0; t < 8; t++) acc[t] = (f32x4){0.f, 0.f, 0.f, 0.f};
    #pragma unroll
    for (int c = 0; c < 6; c++) {
        #pragma unroll
        for (int t = 0; t < 8; t++)
            acc[t] = __builtin_amdgcn_mfma_f32_16x16x32_bf16(
                a[c], B1[(c * 8 + t) * 64 + lane], acc[t], 0, 0, 0);
    }
    #pragma unroll
    for (int t = 0; t < 8; t++) {
        float bb = b1f[t * 16 + l4];
        #pragma unroll
        for (int r = 0; r < 4; r++)
            Hs[(hrow + quad * 4 + r) * 136 + t * 16 + l4] = f2bs_t(silu(acc[t][r] + bb));
    }

    // GEMM2: 128 -> 128, silu
    #pragma unroll
    for (int t = 0; t < 8; t++) acc[t] = (f32x4){0.f, 0.f, 0.f, 0.f};
    #pragma unroll
    for (int c = 0; c < 4; c++) {
        bf16x8 af = *(const bf16x8*)(&Hs[(hrow + l4) * 136 + c * 32 + quad * 8]);
        #pragma unroll
        for (int t = 0; t < 8; t++)
            acc[t] = __builtin_amdgcn_mfma_f32_16x16x32_bf16(
                af, B2[(c * 8 + t) * 64 + lane], acc[t], 0, 0, 0);
    }
    #pragma unroll
    for (int t = 0; t < 8; t++) {
        float bb = b2f[t * 16 + l4];
        #pragma unroll
        for (int r = 0; r < 4; r++)
            Hs[(hrow + quad * 4 + r) * 136 + t * 16 + l4] = f2bs_t(silu(acc[t][r] + bb));
    }

    // GEMM3: 128 -> 192, store mix row straight to global (bf16, RNE)
    f32x4 acc3[12];
    #pragma unroll
    for (int t = 0; t < 12; t++) acc3[t] = (f32x4){0.f, 0.f, 0.f, 0.f};
    #pragma unroll
    for (int c = 0; c < 4; c++) {
        bf16x8 af = *(const bf16x8*)(&Hs[(hrow + l4) * 136 + c * 32 + quad * 8]);
        #pragma unroll
        for (int t = 0; t < 12; t++)
            acc3[t] = __builtin_amdgcn_mfma_f32_16x16x32_bf16(
                af, B3[(c * 12 + t) * 64 + lane], acc3[t], 0, 0, 0);
    }
    #pragma unroll
    for (int t = 0; t < 12; t++) {
        float bb = b3f[t * 16 + l4];
        #pragma unroll
        for (int r = 0; r < 4; r++)
            tpx[(size_t)(ebase + quad * 4 + r) * 192 + t * 16 + l4] =
                f2bs(acc3[t][r] + bb);
    }
}

// ---------------------------------------------------------------------------
// Kernel 3: fused CSR aggregation + node tail. One 64-thread block per node.
// h_v is SoA: h_v[n*192 + c*64 + g] -> coalesced gathers.
// ---------------------------------------------------------------------------
__global__ __launch_bounds__(64, 8) void node_fused_kernel(
    const int* __restrict__ base, const int* __restrict__ cnt,
    const int* __restrict__ sorted_eid, const int* __restrict__ senders,
    const float* __restrict__ vectors,
    const ushort_t* __restrict__ tpx,
    const ushort_t* __restrict__ hs_bf, const float* __restrict__ h_v,
    const int* __restrict__ specie,
    const float* __restrict__ W_dn_s, const float* __restrict__ b_dn_s,
    const float* __restrict__ W_dn_v,
    const float* __restrict__ w_sc_s, const float* __restrict__ w_sc_v,
    const float* __restrict__ W_pb_s, const float* __restrict__ b_pb_s,
    const float* __restrict__ W_pb_v,
    const float* __restrict__ W_r1_s, const float* __restrict__ b_r1_s,
    const float* __restrict__ W_r1_v,
    const float* __restrict__ W_r2_s, const float* __restrict__ b_r2,
    const float* __restrict__ W_r2_v,
    float* __restrict__ out)
{
    __shared__ float as_l[Fd];
    __shared__ float av_l[2 * Fd][3];
    __shared__ float scs[Fd];
    __shared__ float scv[Fd][3];
    __shared__ float ps[Fd];
    __shared__ float pv[Fd][3];
    __shared__ int   eids[64];

    const int n = blockIdx.x;
    const int g = threadIdx.x;  // = f

    // ---- CSR aggregation ----
    const int b = base[n];
    const int c = cnt[n];
    float accS = 0.f;
    float a10 = 0.f, a11 = 0.f, a12 = 0.f;
    float a20 = 0.f, a21 = 0.f, a22 = 0.f;

    for (int done = 0; done < c; done += 64) {
        int m = min(64, c - done);
        __syncthreads();
        if (g < m) eids[g] = sorted_eid[b + done + g];
        __syncthreads();
        for (int i = 0; i < m; i++) {
            const int e  = eids[i];
            const int se = senders[e];
            const float ev0 = SQ3f * vectors[e * 3 + 0];
            const float ev1 = SQ3f * vectors[e * 3 + 1];
            const float ev2 = SQ3f * vectors[e * 3 + 2];
            const float mv0 = h_v[(size_t)se * 192 + 0 * 64 + g];
            const float mv1 = h_v[(size_t)se * 192 + 1 * 64 + g];
            const float mv2 = h_v[(size_t)se * 192 + 2 * 64 + g];
            const float m_s = bs2f(hs_bf[se * 64 + g]);
            const ushort_t* mrow = tpx + (size_t)e * 192;
            const float c0 = bs2f(mrow[g]);
            const float c1 = bs2f(mrow[64 + g]);
            const float c2 = bs2f(mrow[128 + g]);

            float dot = mv0 * ev0 + mv1 * ev1 + mv2 * ev2;
            accS += dot * c0;
            float k1 = m_s * c1;
            a10 += k1 * ev0; a11 += k1 * ev1; a12 += k1 * ev2;
            a20 += (mv1 * ev2 - mv2 * ev1) * c2;
            a21 += (mv2 * ev0 - mv0 * ev2) * c2;
            a22 += (mv0 * ev1 - mv1 * ev0) * c2;
        }
    }
    as_l[g] = accS * (INV_SQ3 * INV_AVG);
    av_l[g][0] = a10 * INV_AVG;
    av_l[g][1] = a11 * INV_AVG;
    av_l[g][2] = a12 * INV_AVG;
    av_l[64 + g][0] = a20 * (INV_SQ2 * INV_AVG);
    av_l[64 + g][1] = a21 * (INV_SQ2 * INV_AVG);
    av_l[64 + g][2] = a22 * (INV_SQ2 * INV_AVG);
    __syncthreads();

    // ---- node tail ----
    float f_s = b_dn_s[g];
    #pragma unroll 8
    for (int f = 0; f < Fd; f++) f_s += as_l[f] * W_dn_s[f * Fd + g];
    float fv0 = 0.f, fv1 = 0.f, fv2 = 0.f;
    #pragma unroll 8
    for (int f = 0; f < 2 * Fd; f++) {
        float w = W_dn_v[f * Fd + g];
        fv0 += av_l[f][0] * w;
        fv1 += av_l[f][1] * w;
        fv2 += av_l[f][2] * w;
    }

    float vv = (fv0 * fv0 + fv1 * fv1 + fv2 * fv2) * INV_SQ3;
    int sp = specie[n];
    float ws0 = w_sc_s[sp * 3 * Fd + 0 * Fd + g];
    float ws1 = w_sc_s[sp * 3 * Fd + 1 * Fd + g];
    float ws2 = w_sc_s[sp * 3 * Fd + 2 * Fd + g];
    float wv0 = w_sc_v[sp * 2 * Fd + 0 * Fd + g];
    float wv1 = w_sc_v[sp * 2 * Fd + 1 * Fd + g];
    float sc_s = ws0 * f_s + ws1 * f_s * f_s + ws2 * vv;
    float kv = wv0 + wv1 * f_s;
    scs[g] = sc_s;
    scv[g][0] = kv * fv0;
    scv[g][1] = kv * fv1;
    scv[g][2] = kv * fv2;
    __syncthreads();

    float p_s = b_pb_s[g];
    float pv0 = 0.f, pv1 = 0.f, pv2 = 0.f;
    #pragma unroll 8
    for (int f = 0; f < Fd; f++) {
        float wps = W_pb_s[f * Fd + g];
        p_s += scs[f] * wps;
        float wpv = W_pb_v[f * Fd + g];
        pv0 += scv[f][0] * wpv;
        pv1 += scv[f][1] * wpv;
        pv2 += scv[f][2] * wpv;
    }
    ps[g] = p_s;
    pv[g][0] = pv0; pv[g][1] = pv1; pv[g][2] = pv2;

    out[OFF_PS + n * Fd + g] = p_s;
    out[OFF_PV + (size_t)n * Fd * 3 + g * 3 + 0] = pv0;
    out[OFF_PV + (size_t)n * Fd * 3 + g * 3 + 1] = pv1;
    out[OFF_PV + (size_t)n * Fd * 3 + g * 3 + 2] = pv2;
    __syncthreads();

    float r0 = b_r1_s[g];
    float r1 = b_r1_s[g + Fd];
    float rv0 = 0.f, rv1 = 0.f, rv2 = 0.f;
    #pragma unroll 8
    for (int f = 0; f < Fd; f++) {
        float p = ps[f];
        r0 += p * W_r1_s[f * 2 * Fd + g];
        r1 += p * W_r1_s[f * 2 * Fd + g + Fd];
        float wrv = W_r1_v[f * Fd + g];
        rv0 += pv[f][0] * wrv;
        rv1 += pv[f][1] * wrv;
        rv2 += pv[f][2] * wrv;
    }
    float act  = silu(r0);
    float gate = silu(r1);
    float o_s = act * W_r2_s[g];
    float wr2v = W_r2_v[g];
    float ov0 = gate * rv0 * wr2v;
    float ov1 = gate * rv1 * wr2v;
    float ov2 = gate * rv2 * wr2v;

    #pragma unroll
    for (int off = 32; off > 0; off >>= 1) {
        o_s += __shfl_down(o_s, off);
        ov0 += __shfl_down(ov0, off);
        ov1 += __shfl_down(ov1, off);
        ov2 += __shfl_down(ov2, off);
    }
    if (g == 0) {
        out[OFF_OS + n] = o_s + b_r2[0];
        out[OFF_OV + n * 3 + 0] = ov0;
        out[OFF_OV + n * 3 + 1] = ov1;
        out[OFF_OV + n * 3 + 2] = ov2;
    }
}

// ---------------------------------------------------------------------------
extern "C" void kernel_launch(void* const* d_in, const int* in_sizes, int n_in,
                              void* d_out, int out_size, void* d_ws, size_t ws_size,
                              hipStream_t stream)
{
    const float* vectors  = (const float*)d_in[0];
    const float* lengths  = (const float*)d_in[1];
    const float* node_s   = (const float*)d_in[2];
    const float* node_v   = (const float*)d_in[3];
    const float* sef      = (const float*)d_in[4];
    const int*  specie    = (const int*)d_in[5];
    const int*  senders   = (const int*)d_in[6];
    const int*  receivers = (const int*)d_in[7];
    const float* W_up_s   = (const float*)d_in[8];
    const float* b_up_s   = (const float*)d_in[9];
    const float* W_up_v   = (const float*)d_in[10];
    const float* mlp_W1   = (const float*)d_in[11];
    const float* mlp_b1   = (const float*)d_in[12];
    const float* mlp_W2   = (const float*)d_in[13];
    const float* mlp_b2   = (const float*)d_in[14];
    const float* mlp_W3   = (const float*)d_in[15];
    const float* mlp_b3   = (const float*)d_in[16];
    const float* W_dn_s   = (const float*)d_in[17];
    const float* b_dn_s   = (const float*)d_in[18];
    const float* W_dn_v   = (const float*)d_in[19];
    const float* w_sc_s   = (const float*)d_in[20];
    const float* w_sc_v   = (const float*)d_in[21];
    const float* W_pb_s   = (const float*)d_in[22];
    const float* b_pb_s   = (const float*)d_in[23];
    const float* W_pb_v   = (const float*)d_in[24];
    const float* W_r1_s   = (const float*)d_in[25];
    const float* b_r1_s   = (const float*)d_in[26];
    const float* W_r1_v   = (const float*)d_in[27];
    const float* W_r2_s   = (const float*)d_in[28];
    const float* b_r2     = (const float*)d_in[29];
    const float* W_r2_v   = (const float*)d_in[30];

    // ws layout: h_v(f32) | tpx(u16) | hs_bf(u16) | Wpacks(u16) | ints
    float* h_v = (float*)d_ws;                                   // N*192 f32
    ushort_t* tpx   = (ushort_t*)(h_v + (size_t)N_ * 192);       // E*192 u16
    ushort_t* hs_bf = tpx + (size_t)E_ * 192;                    // N*64 u16
    ushort_t* W1p   = hs_bf + (size_t)N_ * 64;
    ushort_t* W2p   = W1p + W1P_SZ;
    ushort_t* W3p   = W2p + W2P_SZ;
    int* cnt        = (int*)((((size_t)(W3p + W3P_SZ)) + 15) & ~(size_t)15);
    int* base       = cnt + N_;
    int* cursor     = base + N_;
    int* sorted_eid = cursor + N_;                               // E ints

    float* out = (float*)d_out;

    hipMemsetAsync(cnt, 0, N_ * sizeof(int), stream);

    up_kernel<<<N_, 64, 0, stream>>>(node_s, node_v, W_up_s, b_up_s, W_up_v,
                                     receivers, cnt, hs_bf, h_v);
    pack_kernel<<<256, 256, 0, stream>>>(mlp_W1, mlp_W2, mlp_W3, W1p, W2p, W3p);
    scan_kernel<<<1, 1024, 0, stream>>>(cnt, base, cursor);

    edge_mlp_kernel<<<E_ / 64, 256, 0, stream>>>(
        lengths, sef, senders, receivers,
        mlp_b1, mlp_b2, mlp_b3,
        hs_bf, W1p, W2p, W3p, cursor, sorted_eid, tpx);

    node_fused_kernel<<<N_, 64, 0, stream>>>(
        base, cnt, sorted_eid, senders, vectors,
        tpx, hs_bf, h_v, specie,
        W_dn_s, b_dn_s, W_dn_v, w_sc_s, w_sc_v,
        W_pb_s, b_pb_s, W_pb_v, W_r1_s, b_r1_s, W_r1_v,
        W_r2_s, b_r2, W_r2_v, out);
}